// Round 2
// baseline (1449.539 us; speedup 1.0000x reference)
//
#include <hip/hip_runtime.h>

// LGConv: out = D^{-1/2} A D^{-1/2} x
// x: f32 [N, 64]; edge_index: int32 on device (harness downcasts int64), [2, E]

#define DFEAT 64

__global__ void deg_kernel(const int* __restrict__ dst,
                           float* __restrict__ deg, int E, int N) {
    int e = blockIdx.x * blockDim.x + threadIdx.x;
    if (e < E) {
        unsigned d = (unsigned)dst[e];
        if (d < (unsigned)N) unsafeAtomicAdd(&deg[d], 1.0f);
    }
}

__global__ void dis_kernel(float* __restrict__ deg, int N) {
    int i = blockIdx.x * blockDim.x + threadIdx.x;
    if (i < N) {
        float d = deg[i];
        deg[i] = (d > 0.0f) ? rsqrtf(d) : 0.0f;
    }
}

// 16 lanes per edge; lane c handles float4 chunk c of the 64-float row.
__global__ void scatter_kernel(const float* __restrict__ x,
                               const int* __restrict__ src,
                               const int* __restrict__ dst,
                               const float* __restrict__ dis,
                               float* __restrict__ out, int E, int N) {
    long long t = (long long)blockIdx.x * blockDim.x + threadIdx.x;
    int e = (int)(t >> 4);
    int c = (int)(t & 15);
    if (e >= E) return;

    unsigned s = (unsigned)src[e];
    unsigned d = (unsigned)dst[e];
    if (s >= (unsigned)N || d >= (unsigned)N) return;  // fault guard

    float norm = dis[s] * dis[d];

    const float4 v = *reinterpret_cast<const float4*>(x + (size_t)s * DFEAT + c * 4);
    float* o = out + (size_t)d * DFEAT + c * 4;
    unsafeAtomicAdd(o + 0, v.x * norm);
    unsafeAtomicAdd(o + 1, v.y * norm);
    unsafeAtomicAdd(o + 2, v.z * norm);
    unsafeAtomicAdd(o + 3, v.w * norm);
}

extern "C" void kernel_launch(void* const* d_in, const int* in_sizes, int n_in,
                              void* d_out, int out_size, void* d_ws, size_t ws_size,
                              hipStream_t stream) {
    const float* x   = (const float*)d_in[0];
    const int*   ei  = (const int*)d_in[1];   // harness delivers integer inputs as int32

    const int N = in_sizes[0] / DFEAT;        // 100000
    const int E = in_sizes[1] / 2;            // 1600000
    const int* src = ei;                      // row 0
    const int* dst = ei + E;                  // row 1

    float* deg = (float*)d_ws;                // N floats, becomes deg_inv_sqrt in-place
    float* out = (float*)d_out;

    hipMemsetAsync(deg, 0, (size_t)N * sizeof(float), stream);
    hipMemsetAsync(out, 0, (size_t)out_size * sizeof(float), stream);

    {
        int threads = 256;
        int blocks = (E + threads - 1) / threads;
        deg_kernel<<<blocks, threads, 0, stream>>>(dst, deg, E, N);
    }
    {
        int threads = 256;
        int blocks = (N + threads - 1) / threads;
        dis_kernel<<<blocks, threads, 0, stream>>>(deg, N);
    }
    {
        long long total = (long long)E * 16;
        int threads = 256;
        long long blocks = (total + threads - 1) / threads;
        scatter_kernel<<<(int)blocks, threads, 0, stream>>>(x, src, dst, deg, out, E, N);
    }
}

// Round 3
// 259.869 us; speedup vs baseline: 5.5780x; 5.5780x over previous
//
#include <hip/hip_runtime.h>

// LGConv: out = D^{-1/2} A D^{-1/2} x
// x: f32 [N, 64]; edge_index: int32 on device (harness downcasts int64), [2, E]
// Strategy: build CSR by dst (histogram + scan + fill), then gather per dst
// node with one wave (64 lanes = 64 feature dims). No f32 atomics on out.

#define DFEAT 64
#define SCAN_BLK 256
#define SUMS_BLK 512

// ---------- pass 1: integer degree histogram ----------
__global__ void deg_count_kernel(const int* __restrict__ dst,
                                 int* __restrict__ counts, int E, int N) {
    int e = blockIdx.x * blockDim.x + threadIdx.x;
    if (e < E) {
        unsigned d = (unsigned)dst[e];
        if (d < (unsigned)N) atomicAdd(&counts[d], 1);
    }
}

// ---------- pass 2: dis = deg>0 ? rsqrt(deg) : 0 ----------
__global__ void dis_kernel(const int* __restrict__ counts,
                           float* __restrict__ dis, int N) {
    int i = blockIdx.x * blockDim.x + threadIdx.x;
    if (i < N) {
        int c = counts[i];
        dis[i] = (c > 0) ? rsqrtf((float)c) : 0.0f;
    }
}

// ---------- pass 3: exclusive scan (3 phases) ----------
__global__ void scan_block_kernel(const int* __restrict__ counts,
                                  int* __restrict__ row_ptr,
                                  int* __restrict__ block_sums, int N) {
    __shared__ int tmp[SCAN_BLK];
    int i = blockIdx.x * SCAN_BLK + threadIdx.x;
    int v = (i < N) ? counts[i] : 0;
    tmp[threadIdx.x] = v;
    __syncthreads();
    for (int off = 1; off < SCAN_BLK; off <<= 1) {
        int t = (threadIdx.x >= off) ? tmp[threadIdx.x - off] : 0;
        __syncthreads();
        tmp[threadIdx.x] += t;
        __syncthreads();
    }
    if (i < N) row_ptr[i] = tmp[threadIdx.x] - v;  // exclusive
    if (threadIdx.x == SCAN_BLK - 1) block_sums[blockIdx.x] = tmp[SCAN_BLK - 1];
}

__global__ void scan_sums_kernel(int* __restrict__ block_sums, int nblocks) {
    __shared__ int tmp[SUMS_BLK];
    int v = (threadIdx.x < nblocks) ? block_sums[threadIdx.x] : 0;
    tmp[threadIdx.x] = v;
    __syncthreads();
    for (int off = 1; off < SUMS_BLK; off <<= 1) {
        int t = (threadIdx.x >= off) ? tmp[threadIdx.x - off] : 0;
        __syncthreads();
        tmp[threadIdx.x] += t;
        __syncthreads();
    }
    if (threadIdx.x < nblocks) block_sums[threadIdx.x] = tmp[threadIdx.x] - v;  // exclusive
    if (threadIdx.x == SUMS_BLK - 1) block_sums[nblocks] = tmp[SUMS_BLK - 1];   // total
}

__global__ void add_offsets_kernel(int* __restrict__ row_ptr,
                                   int* __restrict__ cursor,
                                   const int* __restrict__ block_sums,
                                   int N, int nblocks) {
    int i = blockIdx.x * SCAN_BLK + threadIdx.x;
    if (i < N) {
        int r = row_ptr[i] + block_sums[blockIdx.x];
        row_ptr[i] = r;
        cursor[i] = r;
    }
    if (i == 0) row_ptr[N] = block_sums[nblocks];
}

// ---------- pass 4: fill CSR with packed {src, norm} ----------
__global__ void fill_csr_kernel(const int* __restrict__ src,
                                const int* __restrict__ dst,
                                const float* __restrict__ dis,
                                int* __restrict__ cursor,
                                uint2* __restrict__ csr, int E, int N) {
    int e = blockIdx.x * blockDim.x + threadIdx.x;
    if (e >= E) return;
    unsigned s = (unsigned)src[e];
    unsigned d = (unsigned)dst[e];
    if (s >= (unsigned)N || d >= (unsigned)N) return;
    int pos = atomicAdd(&cursor[d], 1);
    float w = dis[s] * dis[d];
    csr[pos] = make_uint2(s, __float_as_uint(w));
}

// ---------- pass 5: gather — one wave per dst node, lane = feature ----------
__global__ void gather_kernel(const float* __restrict__ x,
                              const int* __restrict__ row_ptr,
                              const uint2* __restrict__ csr,
                              float* __restrict__ out, int N) {
    int wid = (int)((blockIdx.x * (long long)blockDim.x + threadIdx.x) >> 6);
    int lane = threadIdx.x & 63;
    if (wid >= N) return;
    int beg = row_ptr[wid];
    int end = row_ptr[wid + 1];
    float acc = 0.0f;
    int k = beg;
    for (; k + 1 < end; k += 2) {
        uint2 e0 = csr[k];
        uint2 e1 = csr[k + 1];
        float v0 = x[(size_t)e0.x * DFEAT + lane];
        float v1 = x[(size_t)e1.x * DFEAT + lane];
        acc += v0 * __uint_as_float(e0.y);
        acc += v1 * __uint_as_float(e1.y);
    }
    if (k < end) {
        uint2 e0 = csr[k];
        acc += x[(size_t)e0.x * DFEAT + lane] * __uint_as_float(e0.y);
    }
    out[(size_t)wid * DFEAT + lane] = acc;
}

// ---------- fallback (round-2 atomic scatter) if ws too small ----------
__global__ void fb_deg_kernel(const int* __restrict__ dst,
                              float* __restrict__ deg, int E, int N) {
    int e = blockIdx.x * blockDim.x + threadIdx.x;
    if (e < E) {
        unsigned d = (unsigned)dst[e];
        if (d < (unsigned)N) unsafeAtomicAdd(&deg[d], 1.0f);
    }
}
__global__ void fb_dis_kernel(float* __restrict__ deg, int N) {
    int i = blockIdx.x * blockDim.x + threadIdx.x;
    if (i < N) {
        float d = deg[i];
        deg[i] = (d > 0.0f) ? rsqrtf(d) : 0.0f;
    }
}
__global__ void fb_scatter_kernel(const float* __restrict__ x,
                                  const int* __restrict__ src,
                                  const int* __restrict__ dst,
                                  const float* __restrict__ dis,
                                  float* __restrict__ out, int E, int N) {
    long long t = (long long)blockIdx.x * blockDim.x + threadIdx.x;
    int e = (int)(t >> 4);
    int c = (int)(t & 15);
    if (e >= E) return;
    unsigned s = (unsigned)src[e];
    unsigned d = (unsigned)dst[e];
    if (s >= (unsigned)N || d >= (unsigned)N) return;
    float norm = dis[s] * dis[d];
    const float4 v = *reinterpret_cast<const float4*>(x + (size_t)s * DFEAT + c * 4);
    float* o = out + (size_t)d * DFEAT + c * 4;
    unsafeAtomicAdd(o + 0, v.x * norm);
    unsafeAtomicAdd(o + 1, v.y * norm);
    unsafeAtomicAdd(o + 2, v.z * norm);
    unsafeAtomicAdd(o + 3, v.w * norm);
}

extern "C" void kernel_launch(void* const* d_in, const int* in_sizes, int n_in,
                              void* d_out, int out_size, void* d_ws, size_t ws_size,
                              hipStream_t stream) {
    const float* x  = (const float*)d_in[0];
    const int*   ei = (const int*)d_in[1];   // harness delivers integer inputs as int32

    const int N = in_sizes[0] / DFEAT;        // 100000
    const int E = in_sizes[1] / 2;            // 1600000
    const int* src = ei;                      // row 0
    const int* dst = ei + E;                  // row 1

    float* out = (float*)d_out;

    const int nblocks_scan = (N + SCAN_BLK - 1) / SCAN_BLK;

    // workspace layout (bytes)
    char* base = (char*)d_ws;
    size_t off = 0;
    int*   cursor     = (int*)(base + off);   off += (size_t)N * 4;          // counts, then bump cursors
    float* dis        = (float*)(base + off); off += (size_t)N * 4;
    int*   row_ptr    = (int*)(base + off);   off += (size_t)(N + 1) * 4;
    int*   block_sums = (int*)(base + off);   off += (size_t)(nblocks_scan + 1) * 4;
    off = (off + 15) & ~(size_t)15;
    uint2* csr        = (uint2*)(base + off); off += (size_t)E * 8;

    const bool csr_ok = (off <= ws_size) && (nblocks_scan <= SUMS_BLK);

    if (csr_ok) {
        hipMemsetAsync(cursor, 0, (size_t)N * 4, stream);

        int eb = (E + 255) / 256;
        deg_count_kernel<<<eb, 256, 0, stream>>>(dst, cursor, E, N);

        int nb = (N + 255) / 256;
        dis_kernel<<<nb, 256, 0, stream>>>(cursor, dis, N);

        scan_block_kernel<<<nblocks_scan, SCAN_BLK, 0, stream>>>(cursor, row_ptr, block_sums, N);
        scan_sums_kernel<<<1, SUMS_BLK, 0, stream>>>(block_sums, nblocks_scan);
        add_offsets_kernel<<<nblocks_scan, SCAN_BLK, 0, stream>>>(row_ptr, cursor, block_sums, N, nblocks_scan);

        fill_csr_kernel<<<eb, 256, 0, stream>>>(src, dst, dis, cursor, csr, E, N);

        long long total = (long long)N * 64;
        int gb = (int)((total + 255) / 256);
        gather_kernel<<<gb, 256, 0, stream>>>(x, row_ptr, csr, out, N);
    } else {
        // fallback: atomic scatter (needs only N floats of ws)
        float* deg = (float*)d_ws;
        hipMemsetAsync(deg, 0, (size_t)N * 4, stream);
        hipMemsetAsync(out, 0, (size_t)out_size * 4, stream);
        int eb = (E + 255) / 256;
        fb_deg_kernel<<<eb, 256, 0, stream>>>(dst, deg, E, N);
        int nb = (N + 255) / 256;
        fb_dis_kernel<<<nb, 256, 0, stream>>>(deg, N);
        long long total = (long long)E * 16;
        int sb = (int)((total + 255) / 256);
        fb_scatter_kernel<<<sb, 256, 0, stream>>>(x, src, dst, deg, out, E, N);
    }
}

// Round 4
// 249.725 us; speedup vs baseline: 5.8045x; 1.0406x over previous
//
#include <hip/hip_runtime.h>

// LGConv: out = D^{-1/2} A D^{-1/2} x
// x: f32 [N, 64]; edge_index: int32 on device (harness downcasts int64), [2, E]
// CSR-by-dst build (histogram + scan + fill), then gather: one wave per dst
// node, lane = feature dim. Gather is latency-bound -> unroll x4 + nontemporal
// csr/out accesses to keep x resident in L2.

#define DFEAT 64
#define SCAN_BLK 256
#define SUMS_BLK 512

// ---------- pass 1: integer degree histogram ----------
__global__ void deg_count_kernel(const int* __restrict__ dst,
                                 int* __restrict__ counts, int E, int N) {
    int e = blockIdx.x * blockDim.x + threadIdx.x;
    if (e < E) {
        unsigned d = (unsigned)dst[e];
        if (d < (unsigned)N) atomicAdd(&counts[d], 1);
    }
}

// ---------- pass 2: block-level exclusive scan, fused dis = rsqrt(deg) ----------
__global__ void scan_block_kernel(const int* __restrict__ counts,
                                  int* __restrict__ row_ptr,
                                  int* __restrict__ block_sums,
                                  float* __restrict__ dis, int N) {
    __shared__ int tmp[SCAN_BLK];
    int i = blockIdx.x * SCAN_BLK + threadIdx.x;
    int v = (i < N) ? counts[i] : 0;
    tmp[threadIdx.x] = v;
    __syncthreads();
    for (int off = 1; off < SCAN_BLK; off <<= 1) {
        int t = (threadIdx.x >= off) ? tmp[threadIdx.x - off] : 0;
        __syncthreads();
        tmp[threadIdx.x] += t;
        __syncthreads();
    }
    if (i < N) {
        row_ptr[i] = tmp[threadIdx.x] - v;                  // exclusive
        dis[i] = (v > 0) ? rsqrtf((float)v) : 0.0f;         // fused pass 2
    }
    if (threadIdx.x == SCAN_BLK - 1) block_sums[blockIdx.x] = tmp[SCAN_BLK - 1];
}

__global__ void scan_sums_kernel(int* __restrict__ block_sums, int nblocks) {
    __shared__ int tmp[SUMS_BLK];
    int v = (threadIdx.x < nblocks) ? block_sums[threadIdx.x] : 0;
    tmp[threadIdx.x] = v;
    __syncthreads();
    for (int off = 1; off < SUMS_BLK; off <<= 1) {
        int t = (threadIdx.x >= off) ? tmp[threadIdx.x - off] : 0;
        __syncthreads();
        tmp[threadIdx.x] += t;
        __syncthreads();
    }
    if (threadIdx.x < nblocks) block_sums[threadIdx.x] = tmp[threadIdx.x] - v;  // exclusive
    if (threadIdx.x == SUMS_BLK - 1) block_sums[nblocks] = tmp[SUMS_BLK - 1];   // total
}

__global__ void add_offsets_kernel(int* __restrict__ row_ptr,
                                   int* __restrict__ cursor,
                                   const int* __restrict__ block_sums,
                                   int N, int nblocks) {
    int i = blockIdx.x * SCAN_BLK + threadIdx.x;
    if (i < N) {
        int r = row_ptr[i] + block_sums[blockIdx.x];
        row_ptr[i] = r;
        cursor[i] = r;
    }
    if (i == 0) row_ptr[N] = block_sums[nblocks];
}

// ---------- pass 4: fill CSR with packed {src, norm} ----------
__global__ void fill_csr_kernel(const int* __restrict__ src,
                                const int* __restrict__ dst,
                                const float* __restrict__ dis,
                                int* __restrict__ cursor,
                                unsigned long long* __restrict__ csr, int E, int N) {
    int e = blockIdx.x * blockDim.x + threadIdx.x;
    if (e >= E) return;
    unsigned s = (unsigned)src[e];
    unsigned d = (unsigned)dst[e];
    if (s >= (unsigned)N || d >= (unsigned)N) return;
    int pos = atomicAdd(&cursor[d], 1);
    float w = dis[s] * dis[d];
    unsigned long long rec = ((unsigned long long)__float_as_uint(w) << 32) | s;
    csr[pos] = rec;
}

// ---------- pass 5: gather — one wave per dst node, lane = feature ----------
__global__ void gather_kernel(const float* __restrict__ x,
                              const int* __restrict__ row_ptr,
                              const unsigned long long* __restrict__ csr,
                              float* __restrict__ out, int N) {
    int wid = (int)((blockIdx.x * (long long)blockDim.x + threadIdx.x) >> 6);
    int lane = threadIdx.x & 63;
    if (wid >= N) return;
    int beg = row_ptr[wid];
    int end = row_ptr[wid + 1];
    float acc = 0.0f;
    int k = beg;
    int n4 = beg + ((end - beg) & ~3);
    for (; k < n4; k += 4) {
        unsigned long long e0 = __builtin_nontemporal_load(csr + k);
        unsigned long long e1 = __builtin_nontemporal_load(csr + k + 1);
        unsigned long long e2 = __builtin_nontemporal_load(csr + k + 2);
        unsigned long long e3 = __builtin_nontemporal_load(csr + k + 3);
        float v0 = x[(size_t)(unsigned)e0 * DFEAT + lane];
        float v1 = x[(size_t)(unsigned)e1 * DFEAT + lane];
        float v2 = x[(size_t)(unsigned)e2 * DFEAT + lane];
        float v3 = x[(size_t)(unsigned)e3 * DFEAT + lane];
        acc += v0 * __uint_as_float((unsigned)(e0 >> 32));
        acc += v1 * __uint_as_float((unsigned)(e1 >> 32));
        acc += v2 * __uint_as_float((unsigned)(e2 >> 32));
        acc += v3 * __uint_as_float((unsigned)(e3 >> 32));
    }
    for (; k < end; ++k) {
        unsigned long long e0 = __builtin_nontemporal_load(csr + k);
        acc += x[(size_t)(unsigned)e0 * DFEAT + lane] * __uint_as_float((unsigned)(e0 >> 32));
    }
    __builtin_nontemporal_store(acc, &out[(size_t)wid * DFEAT + lane]);
}

// ---------- fallback (atomic scatter) if ws too small ----------
__global__ void fb_deg_kernel(const int* __restrict__ dst,
                              float* __restrict__ deg, int E, int N) {
    int e = blockIdx.x * blockDim.x + threadIdx.x;
    if (e < E) {
        unsigned d = (unsigned)dst[e];
        if (d < (unsigned)N) unsafeAtomicAdd(&deg[d], 1.0f);
    }
}
__global__ void fb_dis_kernel(float* __restrict__ deg, int N) {
    int i = blockIdx.x * blockDim.x + threadIdx.x;
    if (i < N) {
        float d = deg[i];
        deg[i] = (d > 0.0f) ? rsqrtf(d) : 0.0f;
    }
}
__global__ void fb_scatter_kernel(const float* __restrict__ x,
                                  const int* __restrict__ src,
                                  const int* __restrict__ dst,
                                  const float* __restrict__ dis,
                                  float* __restrict__ out, int E, int N) {
    long long t = (long long)blockIdx.x * blockDim.x + threadIdx.x;
    int e = (int)(t >> 4);
    int c = (int)(t & 15);
    if (e >= E) return;
    unsigned s = (unsigned)src[e];
    unsigned d = (unsigned)dst[e];
    if (s >= (unsigned)N || d >= (unsigned)N) return;
    float norm = dis[s] * dis[d];
    const float4 v = *reinterpret_cast<const float4*>(x + (size_t)s * DFEAT + c * 4);
    float* o = out + (size_t)d * DFEAT + c * 4;
    unsafeAtomicAdd(o + 0, v.x * norm);
    unsafeAtomicAdd(o + 1, v.y * norm);
    unsafeAtomicAdd(o + 2, v.z * norm);
    unsafeAtomicAdd(o + 3, v.w * norm);
}

extern "C" void kernel_launch(void* const* d_in, const int* in_sizes, int n_in,
                              void* d_out, int out_size, void* d_ws, size_t ws_size,
                              hipStream_t stream) {
    const float* x  = (const float*)d_in[0];
    const int*   ei = (const int*)d_in[1];   // harness delivers integer inputs as int32

    const int N = in_sizes[0] / DFEAT;        // 100000
    const int E = in_sizes[1] / 2;            // 1600000
    const int* src = ei;                      // row 0
    const int* dst = ei + E;                  // row 1

    float* out = (float*)d_out;

    const int nblocks_scan = (N + SCAN_BLK - 1) / SCAN_BLK;

    // workspace layout (bytes)
    char* base = (char*)d_ws;
    size_t off = 0;
    int*   cursor     = (int*)(base + off);   off += (size_t)N * 4;   // counts, then bump cursors
    float* dis        = (float*)(base + off); off += (size_t)N * 4;
    int*   row_ptr    = (int*)(base + off);   off += (size_t)(N + 1) * 4;
    int*   block_sums = (int*)(base + off);   off += (size_t)(nblocks_scan + 1) * 4;
    off = (off + 15) & ~(size_t)15;
    unsigned long long* csr = (unsigned long long*)(base + off); off += (size_t)E * 8;

    const bool csr_ok = (off <= ws_size) && (nblocks_scan <= SUMS_BLK);

    if (csr_ok) {
        hipMemsetAsync(cursor, 0, (size_t)N * 4, stream);

        int eb = (E + 255) / 256;
        deg_count_kernel<<<eb, 256, 0, stream>>>(dst, cursor, E, N);

        scan_block_kernel<<<nblocks_scan, SCAN_BLK, 0, stream>>>(cursor, row_ptr, block_sums, dis, N);
        scan_sums_kernel<<<1, SUMS_BLK, 0, stream>>>(block_sums, nblocks_scan);
        add_offsets_kernel<<<nblocks_scan, SCAN_BLK, 0, stream>>>(row_ptr, cursor, block_sums, N, nblocks_scan);

        fill_csr_kernel<<<eb, 256, 0, stream>>>(src, dst, dis, cursor, csr, E, N);

        long long total = (long long)N * 64;
        int gb = (int)((total + 255) / 256);
        gather_kernel<<<gb, 256, 0, stream>>>(x, row_ptr, csr, out, N);
    } else {
        // fallback: atomic scatter (needs only N floats of ws)
        float* deg = (float*)d_ws;
        hipMemsetAsync(deg, 0, (size_t)N * 4, stream);
        hipMemsetAsync(out, 0, (size_t)out_size * 4, stream);
        int eb = (E + 255) / 256;
        fb_deg_kernel<<<eb, 256, 0, stream>>>(dst, deg, E, N);
        int nb = (N + 255) / 256;
        fb_dis_kernel<<<nb, 256, 0, stream>>>(deg, N);
        long long total = (long long)E * 16;
        int sb = (int)((total + 255) / 256);
        fb_scatter_kernel<<<sb, 256, 0, stream>>>(x, src, dst, deg, out, E, N);
    }
}